// Round 7
// baseline (235.518 us; speedup 1.0000x reference)
//
#include <hip/hip_runtime.h>
#include <stdint.h>

#define A_TOTAL 129600   // 9*120*120 anchors per batch
#define NBATCH 8
#define PRE 3000
#define POST 300
#define NWORD 47         // ceil(3000/64)
#define CAP 6144         // candidate buffer per batch
#define NTILE 1128       // 47*48/2 upper-triangle tiles
#define HBLK 32          // wide-scan blocks per batch
#define JCHUNK 768       // ranksort j-chunk (CAP/JCHUNK = 8 chunks)
#define NJC 8            // CAP / JCHUNK
#define PEND 8           // pipelined full-row loads per window

typedef unsigned long long u64;

__device__ __forceinline__ unsigned xform(float f) {
    unsigned b = __float_as_uint(f);
    return (b & 0x80000000u) ? ~b : (b | 0x80000000u);  // monotonic float->uint
}
__device__ __forceinline__ float unxform(unsigned u) {
    return __uint_as_float((u & 0x80000000u) ? (u & 0x7FFFFFFFu) : ~u);
}
__device__ __forceinline__ u64 readlane64(u64 v, int l) {
    unsigned lo = (unsigned)__builtin_amdgcn_readlane((int)(unsigned)v, l);
    unsigned hi = (unsigned)__builtin_amdgcn_readlane((int)(unsigned)(v >> 32), l);
    return ((u64)hi << 32) | lo;
}

// ---------------- wide 12-bit histogram (bits 20..31) ----------------
__global__ __launch_bounds__(256) void hist1_kernel(const float* __restrict__ cls,
                                                    unsigned* __restrict__ ghist) {
    const int n = blockIdx.y;
    __shared__ unsigned h[4096];
    for (int i = threadIdx.x; i < 4096; i += 256) h[i] = 0u;
    __syncthreads();
    const float4* c4 = (const float4*)(cls + (size_t)n * A_TOTAL);
    const int n4 = A_TOTAL / 4;   // 32400
    for (int i = blockIdx.x * 256 + threadIdx.x; i < n4; i += HBLK * 256) {
        float4 v = c4[i];
        atomicAdd(&h[xform(v.x) >> 20], 1u);
        atomicAdd(&h[xform(v.y) >> 20], 1u);
        atomicAdd(&h[xform(v.z) >> 20], 1u);
        atomicAdd(&h[xform(v.w) >> 20], 1u);
    }
    __syncthreads();
    unsigned* gh = ghist + n * 4096;
    for (int i = threadIdx.x; i < 4096; i += 256)
        if (h[i]) atomicAdd(&gh[i], h[i]);
}

// ---------------- pick coarse bucket; also zero ccount for compact ----------------
__global__ __launch_bounds__(256) void pick1_kernel(const unsigned* __restrict__ ghist,
                                                    unsigned* __restrict__ state,
                                                    int* __restrict__ ccount) {
    const int n = blockIdx.x;
    const int tid = threadIdx.x;
    __shared__ unsigned gsum[256];
    const unsigned* gh = ghist + n * 4096;
    unsigned s = 0;
    for (int q = 0; q < 16; ++q) s += gh[tid * 16 + q];
    gsum[tid] = s;
    __syncthreads();
    if (tid == 0) {
        unsigned acc = 0; int g = 255;
        for (; g > 0; --g) { if (acc + gsum[g] >= PRE) break; acc += gsum[g]; }
        int b = 16 * g + 15;
        for (; b >= 16 * g; --b) { if (acc + gh[b] >= PRE) break; acc += gh[b]; }
        state[n] = ((unsigned)b) << 20;        // coarse threshold
        ccount[n] = 0;
    }
}

// ---------------- wide compaction of all u >= uT (order irrelevant) ----------------
__global__ __launch_bounds__(256) void compact_kernel(const float* __restrict__ cls,
                                                      const unsigned* __restrict__ state,
                                                      u64* __restrict__ cand,
                                                      int* __restrict__ ccount) {
    const int n = blockIdx.y;
    const int tid = threadIdx.x;
    __shared__ u64 lbuf[4096];
    __shared__ unsigned lcnt, lbase;
    if (tid == 0) lcnt = 0u;
    __syncthreads();
    const unsigned uT = state[n];
    const float4* c4 = (const float4*)(cls + (size_t)n * A_TOTAL);
    const int n4 = A_TOTAL / 4;
    for (int i = blockIdx.x * 256 + tid; i < n4; i += HBLK * 256) {
        float4 v = c4[i];
        const float* vf = (const float*)&v;
#pragma unroll
        for (int c = 0; c < 4; ++c) {
            unsigned u = xform(vf[c]);
            if (u >= uT) {
                unsigned slot = atomicAdd(&lcnt, 1u);
                if (slot < 4096u)
                    lbuf[slot] = ((u64)u << 32) | (unsigned)(~(4 * i + c));
            }
        }
    }
    __syncthreads();
    if (tid == 0) lbase = (unsigned)atomicAdd(&ccount[n], (int)min(lcnt, 4096u));
    __syncthreads();
    const unsigned cnt = min(lcnt, 4096u), base = lbase;
    u64* cd = cand + (size_t)n * CAP;
    for (unsigned j = tid; j < cnt; j += 256)
        if (base + j < CAP) cd[base + j] = lbuf[j];
}

// ---------------- partial rank-by-counting: per-chunk slabs, no atomics ----------------
__global__ __launch_bounds__(256) void ranksort_partial(const u64* __restrict__ cand,
                                                        const int* __restrict__ ccount,
                                                        int* __restrict__ grank_part) {
    const int n = blockIdx.z;
    const int C = min(ccount[n], CAP);
    if (blockIdx.x * 256 >= C) return;
    const int j0 = blockIdx.y * JCHUNK;
    if (j0 >= C) return;
    const int tid = threadIdx.x;
    __shared__ u64 k[JCHUNK];
    const u64* cd = cand + (size_t)n * CAP;
    const int jlim = min(JCHUNK, C - j0);
    for (int j = tid; j < JCHUNK; j += 256)
        k[j] = (j < jlim) ? cd[j0 + j] : 0ull;   // 0 never > any real key
    __syncthreads();
    const int i = blockIdx.x * 256 + tid;
    if (i >= C) return;
    const u64 key = cd[i];
    int rank = 0;
    int j = 0;
    for (; j + 8 <= JCHUNK; j += 8) {
        rank += (k[j] > key) + (k[j+1] > key) + (k[j+2] > key) + (k[j+3] > key)
              + (k[j+4] > key) + (k[j+5] > key) + (k[j+6] > key) + (k[j+7] > key);
    }
    grank_part[((size_t)n * NJC + blockIdx.y) * CAP + i] = rank;  // plain store
}

// ---------------- gather: sum partial ranks -> ordered scores + scrambled boxes ----------------
__global__ __launch_bounds__(256) void rank_gather(const u64* __restrict__ cand,
                                                   const int* __restrict__ ccount,
                                                   const int* __restrict__ grank_part,
                                                   const float* __restrict__ bbox,
                                                   float* __restrict__ tscores,
                                                   float* __restrict__ boxes) {
    const int n = blockIdx.y;
    const int C = min(ccount[n], CAP);
    const int i = blockIdx.x * 256 + threadIdx.x;
    if (i >= C) return;
    const int nj = (C + JCHUNK - 1) / JCHUNK;
    int rank = 0;
    for (int jc = 0; jc < nj; ++jc)
        rank += grank_part[((size_t)n * NJC + jc) * CAP + i];
    if (rank >= PRE) return;
    const u64 key = cand[(size_t)n * CAP + i];
    const unsigned u = (unsigned)(key >> 32);
    const int r = (int)(~(unsigned)key);     // original flat index
    tscores[n * PRE + rank] = unxform(u);

    // scrambled box gather (replicates reference reshape bug exactly)
    int kp = r % 9;            // k'
    int pp = r / 9;            // h'*120 + w'
    int s_ch = pp % 36;        // source channel
    int qbase = pp / 36;
    int k2 = s_ch >> 2, j2 = s_ch & 3;
    float ratio = (k2 < 3) ? 0.5f : ((k2 < 6) ? 1.0f : 2.0f);
    int si = k2 % 3;
    float scale = (si == 0) ? 8.0f : ((si == 1) ? 16.0f : 32.0f);
    float sq = sqrtf(ratio);
    float wsk = 16.0f * scale / sq;
    float hsk = 16.0f * scale * sq;
    float* outp = boxes + ((size_t)n * PRE + rank) * 4;
#pragma unroll
    for (int j4 = 0; j4 < 4; ++j4) {
        int c = 4 * kp + j4;
        int q = c * 400 + qbase;       // source spatial h*120+w
        int hh = q / 120, w2 = q % 120;
        float cx = (w2 + 0.5f) * 16.0f;
        float cy = (hh + 0.5f) * 16.0f;
        float a;
        if (j2 == 0)      a = cx - 0.5f * wsk;
        else if (j2 == 1) a = cy - 0.5f * hsk;
        else if (j2 == 2) a = cx + 0.5f * wsk;
        else              a = cy + 0.5f * hsk;
        float d = bbox[((size_t)n * 36 + s_ch) * 14400 + q];
        outp[j4] = fminf(fmaxf(a + d, 0.0f), 1919.0f);
    }
}

// ---------------- IoU bitmask, upper-triangle tiles; also emits packed
// diag/sdiag/s2diag arrays (dpk[n][w][3][64]) for the barrier-free scan ----------------
__global__ __launch_bounds__(256) void nms_mask_kernel(const float* __restrict__ boxes,
                                                       u64* __restrict__ mask,
                                                       u64* __restrict__ dpk) {
    const int n = blockIdx.y;
    const int t = threadIdx.x & 63;
    const int wv = threadIdx.x >> 6;
    const int T = blockIdx.x * 4 + wv;
    const bool active = (T < NTILE);
    __shared__ float cx1[4][64], cy1[4][64], cx2[4][64], cy2[4][64], car[4][64];
    int rb = 0, cb = 0;
    if (active) {
        int off = 0;
        for (int r = 0; r < NWORD; ++r) {
            int row_tiles = NWORD - r;
            if (T < off + row_tiles) { rb = r; cb = r + (T - off); break; }
            off += row_tiles;
        }
        int cj = cb * 64 + t;
        if (cj < PRE) {
            float4 b4 = *(const float4*)(boxes + ((size_t)n * PRE + cj) * 4);
            cx1[wv][t] = b4.x; cy1[wv][t] = b4.y; cx2[wv][t] = b4.z; cy2[wv][t] = b4.w;
            car[wv][t] = (b4.z - b4.x + 1.0f) * (b4.w - b4.y + 1.0f);
        }
    }
    __syncthreads();
    if (!active) return;
    int i = rb * 64 + t;
    if (i >= PRE) return;
    float4 b4 = *(const float4*)(boxes + ((size_t)n * PRE + i) * 4);
    float x1 = b4.x, y1 = b4.y, x2 = b4.z, y2 = b4.w;
    float ai = (x2 - x1 + 1.0f) * (y2 - y1 + 1.0f);
    u64 w = 0ull;
    int lim = min(64, PRE - cb * 64);
    for (int jj = 0; jj < lim; ++jj) {
        float xx1 = fmaxf(x1, cx1[wv][jj]);
        float yy1 = fmaxf(y1, cy1[wv][jj]);
        float xx2 = fminf(x2, cx2[wv][jj]);
        float yy2 = fminf(y2, cy2[wv][jj]);
        float iw = fmaxf(xx2 - xx1 + 1.0f, 0.0f);
        float ih = fmaxf(yy2 - yy1 + 1.0f, 0.0f);
        float inter = iw * ih;
        float iou = inter / (ai + car[wv][jj] - inter);
        if (iou > 0.5f) w |= (1ull << jj);
    }
    mask[((size_t)n * PRE + i) * NWORD + cb] = w;
    const int d = cb - rb;
    if (d <= 2)
        dpk[(((size_t)n * NWORD + rb) * 3 + d) * 64 + t] = w;
}

// ---------------- greedy scan: single wave, NO barriers, depth-2 carry chain.
// Per window: diag (in-window), sdiag (carry to w+1), s2diag (carry to w+2)
// come from packed contiguous arrays; full rows of accepts are fire-and-forget
// loads consumed at w+3 (two windows of latency slack). ----------------
__global__ __launch_bounds__(64) void nms_scan_kernel(const u64* __restrict__ mask,
                                                      const u64* __restrict__ dpk,
                                                      const float* __restrict__ tscores,
                                                      const float* __restrict__ boxes,
                                                      float* __restrict__ out) {
    const int n = blockIdx.x;
    const int lane = threadIdx.x;
    const int lane_cl = min(lane, NWORD - 1);
    __shared__ int kidx[POST];
    const u64* mrow = mask + (size_t)n * PRE * NWORD;
    const u64* dp = dpk + (size_t)n * NWORD * 192;

    // trio ring: windows w, w+1, w+2
    u64 dA, sA, s2A, dB, sB, s2B, dC, sC, s2C;
    {
        const u64* p0 = dp + lane;
        dA = p0[0];   sA = p0[64];        s2A = p0[128];
        dB = p0[192]; sB = p0[192 + 64];  s2B = p0[192 + 128];
        dC = p0[384]; sC = p0[384 + 64];  s2C = p0[384 + 128];
    }
    // pend ring: loads issued at window w consumed at w+3
    u64 pA[PEND], pB[PEND], pC[PEND];
    int nA = 0, nB = 0, nC = 0;
#pragma unroll
    for (int j = 0; j < PEND; ++j) { pA[j] = 0; pB[j] = 0; pC[j] = 0; }

    u64 rem = 0ull;            // lane l holds suppression word l (accepts <= w-3)
    u64 a1 = 0, a2 = 0, prev_c2 = 0;
    int cnt = 0;
    for (int w = 0; w < NWORD; ++w) {
        // consume loads issued at window w-3
#pragma unroll
        for (int j = 0; j < PEND; ++j)
            if (j < nA) rem |= pA[j];
        // scan this window (all control values wave-uniform / scalar)
        const int base = 64 * w;
        const int lim = min(64, PRE - base);
        u64 cur = readlane64(rem, w) | a1 | a2;
        u64 todo = ~cur;
        if (lim < 64) todo &= (1ull << lim) - 1ull;
        u64 alive = 0ull, c1 = 0ull, c2 = 0ull;
        bool full = false;
        while (todo) {
            int b = __ffsll((long long)todo) - 1;
            if (lane == 0) kidx[cnt] = base + b;
            alive |= 1ull << b;
            cnt++;
            if (cnt >= POST) { full = true; break; }
            u64 sup = readlane64(dA, b);      // in-window suppression
            c1 |= readlane64(sA, b);          // carry to word w+1
            c2 |= readlane64(s2A, b);         // carry to word w+2
            todo &= ~(sup | (1ull << b));
        }
        if (full) break;
        a1 = c1; a2 = prev_c2; prev_c2 = c2;
        // rotate pend ring, issue full-row loads for this window's accepts
#pragma unroll
        for (int j = 0; j < PEND; ++j) { pA[j] = pB[j]; pB[j] = pC[j]; }
        nA = nB; nB = nC;
        {
            u64 aw = alive;
            const int na = __popcll(alive);
            if (na) {
#pragma unroll
                for (int j = 0; j < PEND; ++j) {
                    int b = (aw != 0ull) ? (__ffsll((long long)aw) - 1) : 0;
                    pC[j] = mrow[(size_t)(base + b) * NWORD + lane_cl];
                    aw &= aw - 1;
                }
            }
            nC = min(na, PEND);
            while (aw) {                      // rare overflow: blocking update
                int b = __ffsll((long long)aw) - 1; aw &= aw - 1;
                rem |= mrow[(size_t)(base + b) * NWORD + lane_cl];
            }
        }
        // rotate trio ring, prefetch window w+3 (contiguous 512B loads)
        dA = dB; sA = sB; s2A = s2B;
        dB = dC; sB = sC; s2B = s2C;
        const int wn = w + 3;
        if (wn < NWORD) {
            const u64* p = dp + (size_t)wn * 192 + lane;
            dC = p[0];
            sC = (wn + 1 < NWORD) ? p[64] : 0ull;
            s2C = (wn + 2 < NWORD) ? p[128] : 0ull;
        } else { dC = 0ull; sC = 0ull; s2C = 0ull; }
    }
    __syncthreads();
    for (int t = lane; t < POST; t += 64) {
        float* op = out + ((size_t)n * POST + t) * 5;
        if (t < cnt) {
            int i = kidx[t];
            const float* bp = boxes + ((size_t)n * PRE + i) * 4;
            op[1] = bp[0]; op[2] = bp[1]; op[3] = bp[2]; op[4] = bp[3];
        } else {
            op[1] = 0.0f; op[2] = 0.0f; op[3] = 0.0f; op[4] = 0.0f;
        }
        if (n == NBATCH - 1) {
            // reference: score column = batch 7's kept scores, broadcast to all
            float sv = (t < cnt) ? tscores[n * PRE + kidx[t]] : 0.0f;
            for (int m = 0; m < NBATCH; ++m)
                out[((size_t)m * POST + t) * 5] = sv;
        }
    }
}

extern "C" void kernel_launch(void* const* d_in, const int* in_sizes, int n_in,
                              void* d_out, int out_size, void* d_ws, size_t ws_size,
                              hipStream_t stream) {
    const float* cls = (const float*)d_in[0];   // (8,9,120,120)
    const float* bbox = (const float*)d_in[1];  // (8,36,120,120)
    float* out = (float*)d_out;                 // (8,300,5)

    char* p = (char*)d_ws;
    // Overlay: ghist/state/ccount/cand/grank_part are all dead before nms_mask
    // writes mask (stream order), so they live inside the mask region.
    u64* mask = (u64*)p;                               // 8*3000*47*8 = 9,024,000
    unsigned* ghist = (unsigned*)p;                    // 131,072
    unsigned* state = (unsigned*)(p + 131072);         // 32
    int* ccount = (int*)(p + 131200);                  // 32
    u64* cand = (u64*)(p + 131584);                    // 393,216 (ends 524,800)
    int* grank_part = (int*)(p + 524800);              // 8*8*6144*4 = 1,572,864 (ends 2,097,664)
    float* tscores = (float*)(p + 9024000);            // 96,000
    float* boxes = (float*)(p + 9120000);              // 384,000
    u64* dpk = (u64*)(p + 9504000);                    // 8*47*3*64*8 = 577,536 (total 10,081,536)
    (void)ws_size; (void)n_in; (void)in_sizes; (void)out_size;

    hipMemsetAsync(ghist, 0, 131072, stream);
    hist1_kernel<<<dim3(HBLK, NBATCH), 256, 0, stream>>>(cls, ghist);
    pick1_kernel<<<NBATCH, 256, 0, stream>>>(ghist, state, ccount);
    compact_kernel<<<dim3(HBLK, NBATCH), 256, 0, stream>>>(cls, state, cand, ccount);
    ranksort_partial<<<dim3(CAP / 256, NJC, NBATCH), 256, 0, stream>>>(cand, ccount, grank_part);
    rank_gather<<<dim3(CAP / 256, NBATCH), 256, 0, stream>>>(cand, ccount, grank_part, bbox, tscores, boxes);
    nms_mask_kernel<<<dim3((NTILE + 3) / 4, NBATCH), 256, 0, stream>>>(boxes, mask, dpk);
    nms_scan_kernel<<<NBATCH, 64, 0, stream>>>(mask, dpk, tscores, boxes, out);
}

// Round 8
// 225.452 us; speedup vs baseline: 1.0446x; 1.0446x over previous
//
#include <hip/hip_runtime.h>
#include <stdint.h>

#define A_TOTAL 129600   // 9*120*120 anchors per batch
#define NBATCH 8
#define PRE 3000
#define POST 300
#define NWORD 47         // ceil(3000/64)
#define CAP 6144         // candidate buffer per batch
#define NTILE 1128       // 47*48/2 upper-triangle tiles
#define HBLK 32          // wide-scan blocks per batch
#define JCHUNK 768       // ranksort j-chunk (CAP/JCHUNK = 8 chunks)
#define NJC 8            // CAP / JCHUNK
#define WW 192           // scan window width (3 x 64)
#define NWIN 16          // ceil(3000/192)

typedef unsigned long long u64;

__device__ __forceinline__ unsigned xform(float f) {
    unsigned b = __float_as_uint(f);
    return (b & 0x80000000u) ? ~b : (b | 0x80000000u);  // monotonic float->uint
}
__device__ __forceinline__ float unxform(unsigned u) {
    return __uint_as_float((u & 0x80000000u) ? (u & 0x7FFFFFFFu) : ~u);
}
__device__ __forceinline__ u64 readlane64(u64 v, int l) {
    unsigned lo = (unsigned)__builtin_amdgcn_readlane((int)(unsigned)v, l);
    unsigned hi = (unsigned)__builtin_amdgcn_readlane((int)(unsigned)(v >> 32), l);
    return ((u64)hi << 32) | lo;
}

// ---------------- wide 12-bit histogram (bits 20..31) ----------------
__global__ __launch_bounds__(256) void hist1_kernel(const float* __restrict__ cls,
                                                    unsigned* __restrict__ ghist) {
    const int n = blockIdx.y;
    __shared__ unsigned h[4096];
    for (int i = threadIdx.x; i < 4096; i += 256) h[i] = 0u;
    __syncthreads();
    const float4* c4 = (const float4*)(cls + (size_t)n * A_TOTAL);
    const int n4 = A_TOTAL / 4;   // 32400
    for (int i = blockIdx.x * 256 + threadIdx.x; i < n4; i += HBLK * 256) {
        float4 v = c4[i];
        atomicAdd(&h[xform(v.x) >> 20], 1u);
        atomicAdd(&h[xform(v.y) >> 20], 1u);
        atomicAdd(&h[xform(v.z) >> 20], 1u);
        atomicAdd(&h[xform(v.w) >> 20], 1u);
    }
    __syncthreads();
    unsigned* gh = ghist + n * 4096;
    for (int i = threadIdx.x; i < 4096; i += 256)
        if (h[i]) atomicAdd(&gh[i], h[i]);
}

// ---------------- pick coarse bucket; also zero ccount for compact ----------------
__global__ __launch_bounds__(256) void pick1_kernel(const unsigned* __restrict__ ghist,
                                                    unsigned* __restrict__ state,
                                                    int* __restrict__ ccount) {
    const int n = blockIdx.x;
    const int tid = threadIdx.x;
    __shared__ unsigned gsum[256];
    const unsigned* gh = ghist + n * 4096;
    unsigned s = 0;
    for (int q = 0; q < 16; ++q) s += gh[tid * 16 + q];
    gsum[tid] = s;
    __syncthreads();
    if (tid == 0) {
        unsigned acc = 0; int g = 255;
        for (; g > 0; --g) { if (acc + gsum[g] >= PRE) break; acc += gsum[g]; }
        int b = 16 * g + 15;
        for (; b >= 16 * g; --b) { if (acc + gh[b] >= PRE) break; acc += gh[b]; }
        state[n] = ((unsigned)b) << 20;        // coarse threshold
        ccount[n] = 0;
    }
}

// ---------------- wide compaction of all u >= uT (order irrelevant) ----------------
__global__ __launch_bounds__(256) void compact_kernel(const float* __restrict__ cls,
                                                      const unsigned* __restrict__ state,
                                                      u64* __restrict__ cand,
                                                      int* __restrict__ ccount) {
    const int n = blockIdx.y;
    const int tid = threadIdx.x;
    __shared__ u64 lbuf[4096];
    __shared__ unsigned lcnt, lbase;
    if (tid == 0) lcnt = 0u;
    __syncthreads();
    const unsigned uT = state[n];
    const float4* c4 = (const float4*)(cls + (size_t)n * A_TOTAL);
    const int n4 = A_TOTAL / 4;
    for (int i = blockIdx.x * 256 + tid; i < n4; i += HBLK * 256) {
        float4 v = c4[i];
        const float* vf = (const float*)&v;
#pragma unroll
        for (int c = 0; c < 4; ++c) {
            unsigned u = xform(vf[c]);
            if (u >= uT) {
                unsigned slot = atomicAdd(&lcnt, 1u);
                if (slot < 4096u)
                    lbuf[slot] = ((u64)u << 32) | (unsigned)(~(4 * i + c));
            }
        }
    }
    __syncthreads();
    if (tid == 0) lbase = (unsigned)atomicAdd(&ccount[n], (int)min(lcnt, 4096u));
    __syncthreads();
    const unsigned cnt = min(lcnt, 4096u), base = lbase;
    u64* cd = cand + (size_t)n * CAP;
    for (unsigned j = tid; j < cnt; j += 256)
        if (base + j < CAP) cd[base + j] = lbuf[j];
}

// ---------------- partial rank-by-counting: per-chunk slabs, no atomics ----------------
__global__ __launch_bounds__(256) void ranksort_partial(const u64* __restrict__ cand,
                                                        const int* __restrict__ ccount,
                                                        int* __restrict__ grank_part) {
    const int n = blockIdx.z;
    const int C = min(ccount[n], CAP);
    if (blockIdx.x * 256 >= C) return;
    const int j0 = blockIdx.y * JCHUNK;
    if (j0 >= C) return;
    const int tid = threadIdx.x;
    __shared__ u64 k[JCHUNK];
    const u64* cd = cand + (size_t)n * CAP;
    const int jlim = min(JCHUNK, C - j0);
    for (int j = tid; j < JCHUNK; j += 256)
        k[j] = (j < jlim) ? cd[j0 + j] : 0ull;   // 0 never > any real key
    __syncthreads();
    const int i = blockIdx.x * 256 + tid;
    if (i >= C) return;
    const u64 key = cd[i];
    int rank = 0;
    int j = 0;
    for (; j + 8 <= JCHUNK; j += 8) {
        rank += (k[j] > key) + (k[j+1] > key) + (k[j+2] > key) + (k[j+3] > key)
              + (k[j+4] > key) + (k[j+5] > key) + (k[j+6] > key) + (k[j+7] > key);
    }
    grank_part[((size_t)n * NJC + blockIdx.y) * CAP + i] = rank;  // plain store
}

// ---------------- gather: sum partial ranks -> ordered scores + scrambled boxes ----------------
__global__ __launch_bounds__(256) void rank_gather(const u64* __restrict__ cand,
                                                   const int* __restrict__ ccount,
                                                   const int* __restrict__ grank_part,
                                                   const float* __restrict__ bbox,
                                                   float* __restrict__ tscores,
                                                   float* __restrict__ boxes) {
    const int n = blockIdx.y;
    const int C = min(ccount[n], CAP);
    const int i = blockIdx.x * 256 + threadIdx.x;
    if (i >= C) return;
    const int nj = (C + JCHUNK - 1) / JCHUNK;
    int rank = 0;
    for (int jc = 0; jc < nj; ++jc)
        rank += grank_part[((size_t)n * NJC + jc) * CAP + i];
    if (rank >= PRE) return;
    const u64 key = cand[(size_t)n * CAP + i];
    const unsigned u = (unsigned)(key >> 32);
    const int r = (int)(~(unsigned)key);     // original flat index
    tscores[n * PRE + rank] = unxform(u);

    // scrambled box gather (replicates reference reshape bug exactly)
    int kp = r % 9;            // k'
    int pp = r / 9;            // h'*120 + w'
    int s_ch = pp % 36;        // source channel
    int qbase = pp / 36;
    int k2 = s_ch >> 2, j2 = s_ch & 3;
    float ratio = (k2 < 3) ? 0.5f : ((k2 < 6) ? 1.0f : 2.0f);
    int si = k2 % 3;
    float scale = (si == 0) ? 8.0f : ((si == 1) ? 16.0f : 32.0f);
    float sq = sqrtf(ratio);
    float wsk = 16.0f * scale / sq;
    float hsk = 16.0f * scale * sq;
    float* outp = boxes + ((size_t)n * PRE + rank) * 4;
#pragma unroll
    for (int j4 = 0; j4 < 4; ++j4) {
        int c = 4 * kp + j4;
        int q = c * 400 + qbase;       // source spatial h*120+w
        int hh = q / 120, w2 = q % 120;
        float cx = (w2 + 0.5f) * 16.0f;
        float cy = (hh + 0.5f) * 16.0f;
        float a;
        if (j2 == 0)      a = cx - 0.5f * wsk;
        else if (j2 == 1) a = cy - 0.5f * hsk;
        else if (j2 == 2) a = cx + 0.5f * wsk;
        else              a = cy + 0.5f * hsk;
        float d = bbox[((size_t)n * 36 + s_ch) * 14400 + q];
        outp[j4] = fminf(fmaxf(a + d, 0.0f), 1919.0f);
    }
}

// ---------------- IoU bitmask, upper-triangle tiles, 4 tiles per block ----------------
__global__ __launch_bounds__(256) void nms_mask_kernel(const float* __restrict__ boxes,
                                                       u64* __restrict__ mask) {
    const int n = blockIdx.y;
    const int t = threadIdx.x & 63;
    const int wv = threadIdx.x >> 6;
    const int T = blockIdx.x * 4 + wv;
    const bool active = (T < NTILE);
    __shared__ float cx1[4][64], cy1[4][64], cx2[4][64], cy2[4][64], car[4][64];
    int rb = 0, cb = 0;
    if (active) {
        int off = 0;
        for (int r = 0; r < NWORD; ++r) {
            int row_tiles = NWORD - r;
            if (T < off + row_tiles) { rb = r; cb = r + (T - off); break; }
            off += row_tiles;
        }
        int cj = cb * 64 + t;
        if (cj < PRE) {
            float4 b4 = *(const float4*)(boxes + ((size_t)n * PRE + cj) * 4);
            cx1[wv][t] = b4.x; cy1[wv][t] = b4.y; cx2[wv][t] = b4.z; cy2[wv][t] = b4.w;
            car[wv][t] = (b4.z - b4.x + 1.0f) * (b4.w - b4.y + 1.0f);
        }
    }
    __syncthreads();
    if (!active) return;
    int i = rb * 64 + t;
    if (i >= PRE) return;
    float4 b4 = *(const float4*)(boxes + ((size_t)n * PRE + i) * 4);
    float x1 = b4.x, y1 = b4.y, x2 = b4.z, y2 = b4.w;
    float ai = (x2 - x1 + 1.0f) * (y2 - y1 + 1.0f);
    u64 w = 0ull;
    int lim = min(64, PRE - cb * 64);
    for (int jj = 0; jj < lim; ++jj) {
        float xx1 = fmaxf(x1, cx1[wv][jj]);
        float yy1 = fmaxf(y1, cy1[wv][jj]);
        float xx2 = fminf(x2, cx2[wv][jj]);
        float yy2 = fminf(y2, cy2[wv][jj]);
        float iw = fmaxf(xx2 - xx1 + 1.0f, 0.0f);
        float ih = fmaxf(yy2 - yy1 + 1.0f, 0.0f);
        float inter = iw * ih;
        float iou = inter / (ai + car[wv][jj] - inter);
        if (iou > 0.5f) w |= (1ull << jj);
    }
    mask[((size_t)n * PRE + i) * NWORD + cb] = w;
}

// ---------------- greedy scan: 192-wide windows, LDS slabs, double-buffered.
// Wave 0 scans window w (3 row-sets of 64, 3-word todo, symmetric-readlane
// in-window suppression); waves 1..3 prefetch window w+1 (contiguous slab,
// coalesced float4). 16 windows instead of 47 amortizes the barrier drain.
__global__ __launch_bounds__(256) void nms_scan_kernel(const u64* __restrict__ mask,
                                                       const float* __restrict__ tscores,
                                                       const float* __restrict__ boxes,
                                                       float* __restrict__ out) {
    const int n = blockIdx.x;
    const int tid = threadIdx.x;
    const int lane = tid & 63;
    const int wv = tid >> 6;
    __shared__ u64 tile[2][WW * NWORD];   // 2 * 72,192 B
    __shared__ int kidx[POST];
    __shared__ int s_cnt;
    const u64* mrow = mask + (size_t)n * PRE * NWORD;

    // window 0: all threads, coalesced float4 copy (slab is contiguous)
    {
        const float4* src = (const float4*)mrow;
        float4* dst = (float4*)tile[0];
        for (int i = tid; i < WW * NWORD / 2; i += 256) dst[i] = src[i];
    }
    if (tid == 0) s_cnt = 0;
    __syncthreads();

    u64 rem = 0ull;   // wave0: lane l (<47) holds global suppression word l
    for (int w = 0; w < NWIN; ++w) {
        const int buf = w & 1;
        const int base = WW * w;
        if (wv > 0 && w + 1 < NWIN) {          // prefetch next window's slab
            const int nbase = base + WW;
            const int nrows = min(WW, PRE - nbase);
            const float4* src = (const float4*)(mrow + (size_t)nbase * NWORD);
            float4* dst = (float4*)tile[buf ^ 1];
            const int n4 = nrows * NWORD / 2;
            for (int i = tid - 64; i < n4; i += 192) dst[i] = src[i];
        }
        if (wv == 0) {
            int cnt = s_cnt;                   // uniform
            const int lim = min(WW, PRE - base);
            const int w0 = 3 * w;
            const bool q2ok = (w0 + 2 < NWORD);
            // lane l holds words w0..w0+2 of rows base+l, base+64+l, base+128+l
            u64 v00, v01, v02, v10, v11, v12, v20, v21, v22;
            {
                const u64* t0 = &tile[buf][(size_t)lane * NWORD + w0];
                const u64* t1 = &tile[buf][(size_t)(lane + 64) * NWORD + w0];
                const u64* t2 = &tile[buf][(size_t)(lane + 128) * NWORD + w0];
                v00 = t0[0]; v01 = t0[1]; v02 = q2ok ? t0[2] : 0ull;
                v10 = t1[0]; v11 = t1[1]; v12 = q2ok ? t1[2] : 0ull;
                v20 = t2[0]; v21 = t2[1]; v22 = q2ok ? t2[2] : 0ull;
            }
            u64 todo0 = ~readlane64(rem, w0);
            u64 todo1 = ~readlane64(rem, w0 + 1);
            u64 todo2 = q2ok ? ~readlane64(rem, w0 + 2) : 0ull;
            if (lim < 64)       { todo0 &= (1ull << lim) - 1; todo1 = 0; todo2 = 0; }
            else if (lim < 128) { todo1 &= (1ull << (lim - 64)) - 1; todo2 = 0; }
            else if (lim < 192) { todo2 &= (1ull << (lim - 128)) - 1; }
            u64 alive0 = 0, alive1 = 0, alive2 = 0;
            while (todo0 | todo1 | todo2) {
                int q, b;
                if (todo0)      { q = 0; b = __ffsll((long long)todo0) - 1; }
                else if (todo1) { q = 1; b = __ffsll((long long)todo1) - 1; }
                else            { q = 2; b = __ffsll((long long)todo2) - 1; }
                const int p = q * 64 + b;
                if (lane == 0) kidx[cnt] = base + p;
                if (q == 0) alive0 |= 1ull << b;
                else if (q == 1) alive1 |= 1ull << b;
                else alive2 |= 1ull << b;
                cnt++;
                if (cnt >= POST) break;
                u64 s0, s1, s2;   // row p's window words (symmetric IoU)
                if (q == 0)      { s0 = readlane64(v00, b); s1 = readlane64(v01, b); s2 = readlane64(v02, b); }
                else if (q == 1) { s0 = readlane64(v10, b); s1 = readlane64(v11, b); s2 = readlane64(v12, b); }
                else             { s0 = readlane64(v20, b); s1 = readlane64(v21, b); s2 = readlane64(v22, b); }
                todo0 &= ~s0; todo1 &= ~s1; todo2 &= ~s2;    // diag bit clears self
                if (q == 0) todo0 &= ~(1ull << b);
                else if (q == 1) todo1 &= ~(1ull << b);
                else todo2 &= ~(1ull << b);
            }
            // apply accepted rows' full 47-word masks to rem (4-deep LDS reads)
            if (lane < NWORD) {
                for (int q = 0; q < 3; ++q) {
                    u64 t2m = (q == 0) ? alive0 : (q == 1) ? alive1 : alive2;
                    const int roff = q * 64;
                    while (t2m) {
                        int b0 = __ffsll((long long)t2m) - 1; t2m &= t2m - 1;
                        int b1 = b0, b2 = b0, b3 = b0;
                        if (t2m) { b1 = __ffsll((long long)t2m) - 1; t2m &= t2m - 1; }
                        if (t2m) { b2 = __ffsll((long long)t2m) - 1; t2m &= t2m - 1; }
                        if (t2m) { b3 = __ffsll((long long)t2m) - 1; t2m &= t2m - 1; }
                        u64 a0 = tile[buf][(size_t)(roff + b0) * NWORD + lane];
                        u64 a1 = tile[buf][(size_t)(roff + b1) * NWORD + lane];
                        u64 a2 = tile[buf][(size_t)(roff + b2) * NWORD + lane];
                        u64 a3 = tile[buf][(size_t)(roff + b3) * NWORD + lane];
                        rem |= (a0 | a1) | (a2 | a3);
                    }
                }
            }
            if (lane == 0) s_cnt = cnt;
        }
        __syncthreads();
        if (s_cnt >= POST) break;
    }

    const int cnt = s_cnt;
    for (int t = tid; t < POST; t += 256) {
        float* op = out + ((size_t)n * POST + t) * 5;
        if (t < cnt) {
            int i = kidx[t];
            const float* bp = boxes + ((size_t)n * PRE + i) * 4;
            op[1] = bp[0]; op[2] = bp[1]; op[3] = bp[2]; op[4] = bp[3];
        } else {
            op[1] = 0.0f; op[2] = 0.0f; op[3] = 0.0f; op[4] = 0.0f;
        }
        if (n == NBATCH - 1) {
            // reference: score column = batch 7's kept scores, broadcast to all
            float sv = (t < cnt) ? tscores[n * PRE + kidx[t]] : 0.0f;
            for (int m = 0; m < NBATCH; ++m)
                out[((size_t)m * POST + t) * 5] = sv;
        }
    }
}

extern "C" void kernel_launch(void* const* d_in, const int* in_sizes, int n_in,
                              void* d_out, int out_size, void* d_ws, size_t ws_size,
                              hipStream_t stream) {
    const float* cls = (const float*)d_in[0];   // (8,9,120,120)
    const float* bbox = (const float*)d_in[1];  // (8,36,120,120)
    float* out = (float*)d_out;                 // (8,300,5)

    char* p = (char*)d_ws;
    // Overlay: ghist/state/ccount/cand/grank_part are all dead before nms_mask
    // writes mask (stream order), so they live inside the mask region.
    u64* mask = (u64*)p;                               // 8*3000*47*8 = 9,024,000
    unsigned* ghist = (unsigned*)p;                    // 131,072
    unsigned* state = (unsigned*)(p + 131072);         // 32
    int* ccount = (int*)(p + 131200);                  // 32
    u64* cand = (u64*)(p + 131584);                    // 393,216 (ends 524,800)
    int* grank_part = (int*)(p + 524800);              // 8*8*6144*4 = 1,572,864 (ends 2,097,664)
    float* tscores = (float*)(p + 9024000);            // 96,000
    float* boxes = (float*)(p + 9120000);              // 384,000 (total 9,504,000)
    (void)ws_size; (void)n_in; (void)in_sizes; (void)out_size;

    hipMemsetAsync(ghist, 0, 131072, stream);
    hist1_kernel<<<dim3(HBLK, NBATCH), 256, 0, stream>>>(cls, ghist);
    pick1_kernel<<<NBATCH, 256, 0, stream>>>(ghist, state, ccount);
    compact_kernel<<<dim3(HBLK, NBATCH), 256, 0, stream>>>(cls, state, cand, ccount);
    ranksort_partial<<<dim3(CAP / 256, NJC, NBATCH), 256, 0, stream>>>(cand, ccount, grank_part);
    rank_gather<<<dim3(CAP / 256, NBATCH), 256, 0, stream>>>(cand, ccount, grank_part, bbox, tscores, boxes);
    nms_mask_kernel<<<dim3((NTILE + 3) / 4, NBATCH), 256, 0, stream>>>(boxes, mask);
    nms_scan_kernel<<<NBATCH, 256, 0, stream>>>(mask, tscores, boxes, out);
}